// Round 1
// baseline (2540.311 us; speedup 1.0000x reference)
//
#include <hip/hip_runtime.h>

#define Nn 256
#define Mm 512
#define Dd 64
#define EPSF 1e-6f
#define INFF 1e30f
#define BC 8
#define NCHUNK (Nn / BC)   // 32
#define NSTAGE (Mm / 4)    // 128

// workspace layout (float offsets)
#define OFF_D     0                    // d[m][n]        512*256
#define OFF_QC    131072               // qc[nb][j]=q[j][nb]  256*257
#define OFF_P     (OFF_QC + 65792)     // p[257] (padded to 260)
#define OFF_WT    (OFF_P + 260)        // wT[t][n]=w[n][t]    256*256
#define OFF_WS    (OFF_WT + 65536)     // W[n] column sums    256
#define OFF_CBAR  (OFF_WS + 256)       // Cbar[t][n] (in-place pipeline state) 256*256
#define OFF_CROW  (OFF_CBAR + 65536)   // C row handoffs, 128*256
#define OFF_FLAG  (OFF_CROW + 32768)   // flags[stage][chunk], 128*32 ints

__global__ __launch_bounds__(256) void k_init(float* __restrict__ ws) {
  int i = blockIdx.x * 256 + threadIdx.x;   // grid 256 -> i < 65536
  ws[OFF_CBAR + i] = INFF;
  if (i < 256) ws[OFF_WS + i] = 0.f;
  if (i < NSTAGE * NCHUNK) ((int*)(ws + OFF_FLAG))[i] = 0;
}

__global__ __launch_bounds__(256) void k_dist(const float* __restrict__ x,
                                              const float* __restrict__ y,
                                              float* __restrict__ d) {
  __shared__ float xs[Dd];
  int m = blockIdx.x, n = threadIdx.x;
  if (n < Dd) xs[n] = x[m * Dd + n];
  __syncthreads();
  const float4* y4 = (const float4*)(y + n * Dd);
  float acc = 0.f;
#pragma unroll
  for (int k = 0; k < Dd / 4; k++) {
    float4 v = y4[k];
    float a0 = xs[4*k+0] - v.x, a1 = xs[4*k+1] - v.y;
    float a2 = xs[4*k+2] - v.z, a3 = xs[4*k+3] - v.w;
    acc += a0*a0 + a1*a1 + a2*a2 + a3*a3;
  }
  d[m * Nn + n] = sqrtf(acc);
}

// transpose q (257 x 256) -> qc[nb][j] (256 x 257)
__global__ __launch_bounds__(256) void k_qt(const float* __restrict__ q, float* __restrict__ qc) {
  int j = blockIdx.x, nb = threadIdx.x;    // grid 257
  qc[nb * 257 + j] = q[j * Nn + nb];
}

// blocked sequential reachability scan: p += p[nb]*q[:,nb], nb = 0..255
__global__ __launch_bounds__(256) void k_reach(const float* __restrict__ qc, float* __restrict__ p_out) {
  __shared__ float p[257];
  __shared__ float vsnap[64];
  __shared__ float qtile[64][65];
  int tid = threadIdx.x;
  p[tid] = (tid == 0) ? 1.f : 0.f;
  if (tid == 0) p[256] = 0.f;
  __syncthreads();
  for (int g = 0; g < 4; g++) {
    int g0 = g * 64;
    // load in-group 64x64 tile: qtile[k][l] = q[g0+l][g0+k] = qc[(g0+k)*257 + g0+l]
    for (int z = 0; z < 16; z++) {
      int idx = tid + z * 256, k = idx >> 6, l = idx & 63;
      qtile[k][l] = qc[(g0 + k) * 257 + g0 + l];
    }
    __syncthreads();
    // phase 1: sequential in-group solve (wave 0), snapshot p[nb] at its step
    if (tid < 64) {
      float pv = p[g0 + tid];
      for (int k = 0; k < 64; k++) {
        float v = __shfl(pv, k, 64);
        if (tid == k) vsnap[k] = v;
        pv += v * qtile[k][tid];
      }
    }
    __syncthreads();
    // phase 2: apply all 64 rank-1 updates to the full vector
    float acc = p[tid];
    float acc2 = (tid == 0) ? p[256] : 0.f;
    for (int k = 0; k < 64; k++) {
      float v = vsnap[k];
      acc += v * qc[(g0 + k) * 257 + tid];
      if (tid == 0) acc2 += v * qc[(g0 + k) * 257 + 256];
    }
    __syncthreads();
    p[tid] = acc;
    if (tid == 0) p[256] = acc2;
    __syncthreads();
  }
  p_out[tid] = p[tid];
  if (tid == 0) p_out[256] = p[256];
}

// wT[t][n] = (t<n) ? p[t]*q[n][t]/(p[n]+eps) : 0 ; W[n] = sum_t wT[t][n]
__global__ __launch_bounds__(256) void k_wbuild(const float* __restrict__ qc, const float* __restrict__ p,
                                                float* __restrict__ wT, float* __restrict__ Wsum) {
  int t = blockIdx.x, n = threadIdx.x;
  float v = 0.f;
  if (t < n) v = p[t] * qc[t * 257 + n] / (p[n] + EPSF);
  wT[t * Nn + n] = v;
  if (v != 0.f) atomicAdd(&Wsum[n], v);
}

__global__ __launch_bounds__(256) void k_main(const float* __restrict__ d, const float* __restrict__ wT,
                                              const float* __restrict__ Wsum, float* __restrict__ cbarG,
                                              float* __restrict__ crowG, int* __restrict__ flags) {
  int b = blockIdx.x;
  int stage = (b & 7) * 16 + (b >> 3);     // consecutive stages share an XCD (b%8 round-robin)
  int tid = threadIdx.x, wave = tid >> 6, lane = tid & 63;
  int m = stage * 4 + wave;
  __shared__ __align__(16) float cbuf[BC][Nn];
  __shared__ __align__(16) float wbuf[BC][Nn];
  __shared__ float Wt[BC];
  __shared__ float cpub[5][BC];            // cpub[w][tt] = C[row w-1][t]; cpub[0] from upstream
  float S[4] = {0.f, 0.f, 0.f, 0.f};
  float4 dnv = *(const float4*)(d + m * Nn + 4 * lane);
  float dnk[4] = {dnv.x, dnv.y, dnv.z, dnv.w};

  for (int j = 0; j < NCHUNK; j++) {
    if (stage > 0 && tid == 0) {
      while (__hip_atomic_load(&flags[(stage - 1) * NCHUNK + j], __ATOMIC_ACQUIRE,
                               __HIP_MEMORY_SCOPE_AGENT) == 0) {
        __builtin_amdgcn_s_sleep(2);
      }
    }
    __syncthreads();
    {
      const float4* src  = (const float4*)(cbarG + j * BC * Nn);
      const float4* wsrc = (const float4*)(wT + j * BC * Nn);
      float4* dst  = (float4*)&cbuf[0][0];
      float4* wdst = (float4*)&wbuf[0][0];
      for (int f = tid; f < BC * Nn / 4; f += 256) { dst[f] = src[f]; wdst[f] = wsrc[f]; }
      if (tid < BC) {
        Wt[tid] = Wsum[j * BC + tid];
        cpub[0][tid] = (stage == 0) ? INFF : crowG[(stage - 1) * Nn + j * BC + tid];
      }
    }
    __syncthreads();

    for (int s_ = 0; s_ < BC + 3; s_++) {
      int tt = s_ - wave;
      if (tt >= 0 && tt < BC) {
        int t = j * BC + tt;
        int owner = t >> 2, comp = t & 3;
        float dsel = (comp == 0) ? dnk[0] : (comp == 1) ? dnk[1] : (comp == 2) ? dnk[2] : dnk[3];
        float Ssel = (comp == 0) ? S[0]   : (comp == 1) ? S[1]   : (comp == 2) ? S[2]   : S[3];
        float d_t = __shfl(dsel, owner, 64);
        float S_t = __shfl(Ssel, owner, 64);
        float Cprev = cpub[wave][tt];
        float C_t;
        if (t == 0) C_t = d_t + ((m == 0) ? 0.f : Cprev);
        else        C_t = fmaf(d_t, Wt[tt], S_t);
        float cmin2 = fminf(C_t, Cprev);
        if (lane == 0) cpub[wave + 1][tt] = C_t;
        float4 cb = *(float4*)&cbuf[tt][4 * lane];
        float4 wv = *(float4*)&wbuf[tt][4 * lane];
        float cbk[4] = {cb.x, cb.y, cb.z, cb.w};
        float wvk[4] = {wv.x, wv.y, wv.z, wv.w};
#pragma unroll
        for (int k = 0; k < 4; k++) {
          if (wvk[k] > 0.f) {
            float a = fminf(cmin2, cbk[k]);
            S[k] = fmaf(wvk[k], a, S[k]);
            cbk[k] = dnk[k] + a;
          }
        }
        cb.x = cbk[0]; cb.y = cbk[1]; cb.z = cbk[2]; cb.w = cbk[3];
        *(float4*)&cbuf[tt][4 * lane] = cb;
      }
      __syncthreads();
    }
    {
      float4* dstg = (float4*)(cbarG + j * BC * Nn);
      const float4* srcl = (const float4*)&cbuf[0][0];
      for (int f = tid; f < BC * Nn / 4; f += 256) dstg[f] = srcl[f];
      if (tid < BC) crowG[stage * Nn + j * BC + tid] = cpub[4][tid];
    }
    __threadfence();
    __syncthreads();
    if (tid == 0)
      __hip_atomic_store(&flags[stage * NCHUNK + j], 1, __ATOMIC_RELEASE, __HIP_MEMORY_SCOPE_AGENT);
  }
}

__global__ __launch_bounds__(256) void k_final(const float* __restrict__ q, const float* __restrict__ p,
                                               const float* __restrict__ crowG, float* __restrict__ out) {
  __shared__ float red[256];
  int n = threadIdx.x;
  float c = crowG[(NSTAGE - 1) * Nn + n];
  float fw = p[n] * q[Nn * Nn + n] / (p[Nn] + EPSF);
  red[n] = fw * c;
  __syncthreads();
  for (int sft = 128; sft > 0; sft >>= 1) {
    if (n < sft) red[n] += red[n + sft];
    __syncthreads();
  }
  if (n == 0) out[0] = red[0];
}

extern "C" void kernel_launch(void* const* d_in, const int* in_sizes, int n_in,
                              void* d_out, int out_size, void* d_ws, size_t ws_size,
                              hipStream_t stream) {
  const float* x = (const float*)d_in[0];
  const float* y = (const float*)d_in[1];
  const float* q = (const float*)d_in[2];
  float* ws = (float*)d_ws;
  float* out = (float*)d_out;
  hipLaunchKernelGGL(k_init,  dim3(256), dim3(256), 0, stream, ws);
  hipLaunchKernelGGL(k_dist,  dim3(Mm),  dim3(Nn),  0, stream, x, y, ws + OFF_D);
  hipLaunchKernelGGL(k_qt,    dim3(257), dim3(Nn),  0, stream, q, ws + OFF_QC);
  hipLaunchKernelGGL(k_reach, dim3(1),   dim3(256), 0, stream, ws + OFF_QC, ws + OFF_P);
  hipLaunchKernelGGL(k_wbuild,dim3(Nn),  dim3(Nn),  0, stream, ws + OFF_QC, ws + OFF_P,
                     ws + OFF_WT, ws + OFF_WS);
  hipLaunchKernelGGL(k_main,  dim3(NSTAGE), dim3(256), 0, stream, ws + OFF_D, ws + OFF_WT,
                     ws + OFF_WS, ws + OFF_CBAR, ws + OFF_CROW, (int*)(ws + OFF_FLAG));
  hipLaunchKernelGGL(k_final, dim3(1),   dim3(256), 0, stream, q, ws + OFF_P, ws + OFF_CROW, out);
}

// Round 2
// 579.409 us; speedup vs baseline: 4.3843x; 4.3843x over previous
//
#include <hip/hip_runtime.h>

typedef float f4 __attribute__((ext_vector_type(4)));

#define Nn 256
#define Mm 512
#define Dd 64
#define EPSF 1e-6f
#define INFF 1e30f
#define BC 8
#define NCHUNK (Nn / BC)   // 32
#define R 16               // rows per stage (one wave)
#define SST (Mm / R)       // 32 stages

// workspace layout (float offsets)
#define OFF_D     0                    // d[m][n]        512*256
#define OFF_QC    131072               // qc[nb][j]=q[j][nb]  256*257
#define OFF_P     (OFF_QC + 65792)     // p[257]
#define OFF_WT    (OFF_P + 260)        // wT[t][n]=w[n][t]    256*256
#define OFF_WS    (OFF_WT + 65536)     // W[n] column sums    256
#define OFF_CBAR  (OFF_WS + 256)       // Cbar[t][n] in-place pipeline state 256*256
#define OFF_CROW  (OFF_CBAR + 65536)   // C row handoffs, SST*256
#define OFF_FLAG  (OFF_CROW + SST*Nn)  // flags[stage][chunk], SST*NCHUNK ints

// ---------------- LLC-coherent (sc0 sc1) access helpers ----------------
__device__ __forceinline__ int llc_load_int(const int* p) {
  int v;
  asm volatile("global_load_dword %0, %1, off sc0 sc1\n\ts_waitcnt vmcnt(0)"
               : "=v"(v) : "v"(p) : "memory");
  return v;
}
__device__ __forceinline__ void llc_store_int(int* p, int v) {
  asm volatile("global_store_dword %0, %1, off sc0 sc1" :: "v"(p), "v"(v) : "memory");
}
// 8 cbar rows (no crow) — stage 0
__device__ __forceinline__ void llc_load_cbar8(const float* b0, f4 c[8]) {
  const float* b1 = b0 + 4 * Nn;
  asm volatile(
    "global_load_dwordx4 %0, %8, off sc0 sc1\n\t"
    "global_load_dwordx4 %1, %8, off offset:1024 sc0 sc1\n\t"
    "global_load_dwordx4 %2, %8, off offset:2048 sc0 sc1\n\t"
    "global_load_dwordx4 %3, %8, off offset:3072 sc0 sc1\n\t"
    "global_load_dwordx4 %4, %9, off sc0 sc1\n\t"
    "global_load_dwordx4 %5, %9, off offset:1024 sc0 sc1\n\t"
    "global_load_dwordx4 %6, %9, off offset:2048 sc0 sc1\n\t"
    "global_load_dwordx4 %7, %9, off offset:3072 sc0 sc1\n\t"
    "s_waitcnt vmcnt(0)"
    : "=v"(c[0]), "=v"(c[1]), "=v"(c[2]), "=v"(c[3]),
      "=v"(c[4]), "=v"(c[5]), "=v"(c[6]), "=v"(c[7])
    : "v"(b0), "v"(b1)
    : "memory");
}
// 8 cbar rows + 2 crow vectors in one round trip — stage > 0
__device__ __forceinline__ void llc_load_cbar10(const float* b0, const float* cp,
                                                f4 c[8], f4& pl, f4& ph) {
  const float* b1 = b0 + 4 * Nn;
  asm volatile(
    "global_load_dwordx4 %0, %10, off sc0 sc1\n\t"
    "global_load_dwordx4 %1, %10, off offset:1024 sc0 sc1\n\t"
    "global_load_dwordx4 %2, %10, off offset:2048 sc0 sc1\n\t"
    "global_load_dwordx4 %3, %10, off offset:3072 sc0 sc1\n\t"
    "global_load_dwordx4 %4, %11, off sc0 sc1\n\t"
    "global_load_dwordx4 %5, %11, off offset:1024 sc0 sc1\n\t"
    "global_load_dwordx4 %6, %11, off offset:2048 sc0 sc1\n\t"
    "global_load_dwordx4 %7, %11, off offset:3072 sc0 sc1\n\t"
    "global_load_dwordx4 %8, %12, off sc0 sc1\n\t"
    "global_load_dwordx4 %9, %12, off offset:16 sc0 sc1\n\t"
    "s_waitcnt vmcnt(0)"
    : "=v"(c[0]), "=v"(c[1]), "=v"(c[2]), "=v"(c[3]),
      "=v"(c[4]), "=v"(c[5]), "=v"(c[6]), "=v"(c[7]),
      "=v"(pl), "=v"(ph)
    : "v"(b0), "v"(b1), "v"(cp)
    : "memory");
}
__device__ __forceinline__ void llc_store_cbar8(float* b0, const f4 c[8]) {
  float* b1 = b0 + 4 * Nn;
  asm volatile(
    "global_store_dwordx4 %8, %0, off sc0 sc1\n\t"
    "global_store_dwordx4 %8, %1, off offset:1024 sc0 sc1\n\t"
    "global_store_dwordx4 %8, %2, off offset:2048 sc0 sc1\n\t"
    "global_store_dwordx4 %8, %3, off offset:3072 sc0 sc1\n\t"
    "global_store_dwordx4 %9, %4, off sc0 sc1\n\t"
    "global_store_dwordx4 %9, %5, off offset:1024 sc0 sc1\n\t"
    "global_store_dwordx4 %9, %6, off offset:2048 sc0 sc1\n\t"
    "global_store_dwordx4 %9, %7, off offset:3072 sc0 sc1\n\t"
    "s_waitcnt vmcnt(0)"
    :: "v"(c[0]), "v"(c[1]), "v"(c[2]), "v"(c[3]),
       "v"(c[4]), "v"(c[5]), "v"(c[6]), "v"(c[7]),
       "v"(b0), "v"(b1)
    : "memory");
}
__device__ __forceinline__ float rdlane(float v, int l) {
  return __int_as_float(__builtin_amdgcn_readlane(__float_as_int(v), l));
}

// ---------------- setup kernels ----------------
__global__ __launch_bounds__(256) void k_init(float* __restrict__ ws) {
  int i = blockIdx.x * 256 + threadIdx.x;   // grid 256 -> i < 65536
  ws[OFF_CBAR + i] = INFF;
  if (i < 256) ws[OFF_WS + i] = 0.f;
  if (i < SST * NCHUNK) ((int*)(ws + OFF_FLAG))[i] = 0;
}

__global__ __launch_bounds__(256) void k_dist(const float* __restrict__ x,
                                              const float* __restrict__ y,
                                              float* __restrict__ d) {
  __shared__ float xs[Dd];
  int m = blockIdx.x, n = threadIdx.x;
  if (n < Dd) xs[n] = x[m * Dd + n];
  __syncthreads();
  const float4* y4 = (const float4*)(y + n * Dd);
  float acc = 0.f;
#pragma unroll
  for (int k = 0; k < Dd / 4; k++) {
    float4 v = y4[k];
    float a0 = xs[4*k+0] - v.x, a1 = xs[4*k+1] - v.y;
    float a2 = xs[4*k+2] - v.z, a3 = xs[4*k+3] - v.w;
    acc += a0*a0 + a1*a1 + a2*a2 + a3*a3;
  }
  d[m * Nn + n] = sqrtf(acc);
}

__global__ __launch_bounds__(256) void k_qt(const float* __restrict__ q, float* __restrict__ qc) {
  int j = blockIdx.x, nb = threadIdx.x;    // grid 257
  qc[nb * 257 + j] = q[j * Nn + nb];
}

__global__ __launch_bounds__(256) void k_reach(const float* __restrict__ qc, float* __restrict__ p_out) {
  __shared__ float p[257];
  __shared__ float vsnap[64];
  __shared__ float qtile[64][65];
  int tid = threadIdx.x;
  p[tid] = (tid == 0) ? 1.f : 0.f;
  if (tid == 0) p[256] = 0.f;
  __syncthreads();
  for (int g = 0; g < 4; g++) {
    int g0 = g * 64;
    for (int z = 0; z < 16; z++) {
      int idx = tid + z * 256, k = idx >> 6, l = idx & 63;
      qtile[k][l] = qc[(g0 + k) * 257 + g0 + l];
    }
    __syncthreads();
    if (tid < 64) {
      float pv = p[g0 + tid];
      for (int k = 0; k < 64; k++) {
        float v = __shfl(pv, k, 64);
        if (tid == k) vsnap[k] = v;
        pv += v * qtile[k][tid];
      }
    }
    __syncthreads();
    float acc = p[tid];
    float acc2 = (tid == 0) ? p[256] : 0.f;
    for (int k = 0; k < 64; k++) {
      float v = vsnap[k];
      acc += v * qc[(g0 + k) * 257 + tid];
      if (tid == 0) acc2 += v * qc[(g0 + k) * 257 + 256];
    }
    __syncthreads();
    p[tid] = acc;
    if (tid == 0) p[256] = acc2;
    __syncthreads();
  }
  p_out[tid] = p[tid];
  if (tid == 0) p_out[256] = p[256];
}

__global__ __launch_bounds__(256) void k_wbuild(const float* __restrict__ qc, const float* __restrict__ p,
                                                float* __restrict__ wT, float* __restrict__ Wsum) {
  int t = blockIdx.x, n = threadIdx.x;
  float v = 0.f;
  if (t < n) v = p[t] * qc[t * 257 + n] / (p[n] + EPSF);
  wT[t * Nn + n] = v;
  if (v != 0.f) atomicAdd(&Wsum[n], v);
}

// ---------------- main systolic DP: 32 single-wave stages ----------------
__global__ __launch_bounds__(64, 1) void k_main(const float* __restrict__ d,
                                                const float* __restrict__ wT,
                                                const float* __restrict__ Wsum,
                                                float* __restrict__ cbarG,
                                                float* __restrict__ crowG,
                                                int* __restrict__ flags) {
  const int stage = blockIdx.x;
  const int lane = threadIdx.x;      // 0..63, owns columns 4*lane .. 4*lane+3
  const int m0 = stage * R;

  f4 dl[R], S[R];
#pragma unroll
  for (int r = 0; r < R; r++) {
    dl[r] = *(const f4*)(d + (m0 + r) * Nn + 4 * lane);
    S[r] = (f4){0.f, 0.f, 0.f, 0.f};
  }
  f4 Wt = *(const f4*)(Wsum + 4 * lane);

#pragma clang loop unroll(disable)
  for (int j = 0; j < NCHUNK; j++) {
    // wT chunk: plain cached loads (read-only, L2-resident) — issue before poll
    f4 wv[BC];
#pragma unroll
    for (int tt = 0; tt < BC; tt++)
      wv[tt] = *(const f4*)(wT + (j * BC + tt) * Nn + 4 * lane);

    if (stage > 0) {
      const int* fp = flags + (stage - 1) * NCHUNK + j;
      while (llc_load_int(fp) == 0) __builtin_amdgcn_s_sleep(1);
    }

    f4 c[BC], cpl, cph;
    float* b0 = cbarG + (size_t)j * BC * Nn + 4 * lane;
    if (stage > 0) {
      llc_load_cbar10(b0, crowG + (stage - 1) * Nn + j * BC, c, cpl, cph);
    } else {
      llc_load_cbar8(b0, c);
      cpl = (f4){INFF, INFF, INFF, INFF};
      cph = cpl;
    }

    f4 clast4;
    const bool isJ0 = (j == 0);
#pragma unroll
    for (int tt = 0; tt < BC; tt++) {
      const int owner = 2 * j + (tt >> 2);   // wave-uniform
      const int comp = tt & 3;               // == t & 3 (compile-time)
      const bool isT0 = isJ0 && (tt == 0);

      float up = (tt < 4) ? cpl[comp] : cph[comp];   // upstream C[m0-1][t]
      float prcMin = up;                              // for cmin2
      float prcVal = up;                              // for the t==0 value chain
      if (isT0 && stage == 0) prcVal = 0.f;
      float cml[R];
#pragma unroll
      for (int r = 0; r < R; r++) {
        float Cv;
        if (isT0) Cv = dl[r][0] + prcVal;                       // C[m][0] = d + C[m-1][0]
        else      Cv = fmaf(dl[r][comp], Wt[comp], S[r][comp]); // C[m][t] = d*W + S
        cml[r] = fminf(Cv, prcMin);                             // cmin2 = min(C[m][t], C[m-1][t])
        prcVal = Cv;
        prcMin = Cv;
      }
      // broadcast owner lane's cmin2 chain + last-row C to all lanes
      float cmB[R];
#pragma unroll
      for (int r = 0; r < R; r++) cmB[r] = rdlane(cml[r], owner);
      float clastv = rdlane(prcVal, owner);
      if (lane == owner) clast4[comp] = clastv;

      // stream update: for each owned column n, chain Cbar through 16 rows
#pragma unroll
      for (int k = 0; k < 4; k++) {
        float w_ = wv[tt][k];
        if (w_ > 0.f) {
          float cbv = c[tt][k];
#pragma unroll
          for (int r = 0; r < R; r++) {
            float a = fminf(cmB[r], cbv);
            S[r][k] = fmaf(w_, a, S[r][k]);
            cbv = dl[r][k] + a;
          }
          c[tt][k] = cbv;
        }
      }
    }

    // handoff: crow (owner lanes), cbar (all lanes), then flag after vmcnt drain
    if (lane == 2 * j || lane == 2 * j + 1) {
      float* cp = crowG + stage * Nn + j * BC + (lane & 1) * 4;
      asm volatile("global_store_dwordx4 %0, %1, off sc0 sc1" :: "v"(cp), "v"(clast4) : "memory");
    }
    llc_store_cbar8(b0, c);          // ends with s_waitcnt vmcnt(0) — covers crow store too
    if (lane == 0) llc_store_int(flags + stage * NCHUNK + j, 1);
  }
}

__global__ __launch_bounds__(256) void k_final(const float* __restrict__ q, const float* __restrict__ p,
                                               const float* __restrict__ crowG, float* __restrict__ out) {
  __shared__ float red[256];
  int n = threadIdx.x;
  float c = crowG[(SST - 1) * Nn + n];
  float fw = p[n] * q[Nn * Nn + n] / (p[Nn] + EPSF);
  red[n] = fw * c;
  __syncthreads();
  for (int sft = 128; sft > 0; sft >>= 1) {
    if (n < sft) red[n] += red[n + sft];
    __syncthreads();
  }
  if (n == 0) out[0] = red[0];
}

extern "C" void kernel_launch(void* const* d_in, const int* in_sizes, int n_in,
                              void* d_out, int out_size, void* d_ws, size_t ws_size,
                              hipStream_t stream) {
  const float* x = (const float*)d_in[0];
  const float* y = (const float*)d_in[1];
  const float* q = (const float*)d_in[2];
  float* ws = (float*)d_ws;
  float* out = (float*)d_out;
  hipLaunchKernelGGL(k_init,  dim3(256), dim3(256), 0, stream, ws);
  hipLaunchKernelGGL(k_dist,  dim3(Mm),  dim3(Nn),  0, stream, x, y, ws + OFF_D);
  hipLaunchKernelGGL(k_qt,    dim3(257), dim3(Nn),  0, stream, q, ws + OFF_QC);
  hipLaunchKernelGGL(k_reach, dim3(1),   dim3(256), 0, stream, ws + OFF_QC, ws + OFF_P);
  hipLaunchKernelGGL(k_wbuild,dim3(Nn),  dim3(Nn),  0, stream, ws + OFF_QC, ws + OFF_P,
                     ws + OFF_WT, ws + OFF_WS);
  hipLaunchKernelGGL(k_main,  dim3(SST), dim3(64),  0, stream, ws + OFF_D, ws + OFF_WT,
                     ws + OFF_WS, ws + OFF_CBAR, ws + OFF_CROW, (int*)(ws + OFF_FLAG));
  hipLaunchKernelGGL(k_final, dim3(1),   dim3(256), 0, stream, q, ws + OFF_P, ws + OFF_CROW, out);
}